// Round 6
// baseline (516.312 us; speedup 1.0000x reference)
//
#include <hip/hip_runtime.h>

// FDTD 2-step update, float32.
// Fields: E (B,1024,1024), Hx (B,1022,1023), Hy (B,1023,1022), B=8.
// v5: 2 launches. Each fused kernel does amper -> (LDS) -> faraday:
//   block = (xt in {0,1}, batch b, 8-row strip y0), 256 threads.
//   Phase 1: compute E_new over halo window rows [y0-2,y0+10], cols
//            [xb-4,xb+524) (verified v2 amper paths, global loads),
//            store to LDS; write own 8x512 rows to global.
//   Phase 2: faraday for own strip reading E_new from LDS (verified v4
//            faraday paths), Hx/Hy from global.

#define KF0 (-11.0f / 12.0f)
#define KF1 (1.5f)
#define KF2 (-0.75f)
#define KF3 (1.0f / 6.0f)
#define KB0 (-1.0f / 6.0f)
#define KB1 (0.75f)
#define KB2 (-1.5f)
#define KB3 (11.0f / 12.0f)

typedef float f4 __attribute__((ext_vector_type(4)));

__device__ __forceinline__ f4 ld4(const float* p) { f4 v; __builtin_memcpy(&v, p, 16); return v; }
__device__ __forceinline__ void st4(float* p, f4 v) { __builtin_memcpy(p, &v, 16); }

#define LOAD6(dst, p) do { __builtin_memcpy(dst, p, 24); } while (0)
#define LOAD4(dst, p) do { __builtin_memcpy(dst, p, 16); } while (0)

// ---- scalar amper (verified v2), global loads ----
__device__ __forceinline__ float amper_pt(const float* __restrict__ e,
                                          const float* __restrict__ hx,
                                          const float* __restrict__ hy,
                                          int y, int x)
{
    float v = e[y * 1024 + x];
    if ((y >= 2) & (y < 1022) & (x >= 2) & (x < 1022)) {
        const float* r0 = hy + (y - 2) * 1022 + (x - 2);
        const float* r1 = r0 + 1022;
        const float* r2 = r1 + 1022;
        v += 0.5f * ((r0[0] + r0[2])
                     - (r1[0] + r1[1] + r1[2])
                     + (r2[0] + r2[1] + r2[2]));
        const float* q0 = hx + (y - 2) * 1023 + (x - 2);
        const float* q1 = q0 + 1023;
        const float* q2 = q1 + 1023;
        v -= 0.5f * ((q0[0] - q0[1] + q0[2])
                     + (-q1[1] + q1[2])
                     + (q2[0] - q2[1] + q2[2]));
    }
    bool cx = (x >= 1) & (x < 1023);
    if ((y < 1020) & cx) {
        const float* c = hy + y * 1022 + (x - 1);
        v += KF0 * c[0] + KF1 * c[1022] + KF2 * c[2044] + KF3 * c[3066];
    }
    if ((y >= 4) & cx) {
        const float* c = hy + (y - 4) * 1022 + (x - 1);
        v += KB0 * c[0] + KB1 * c[1022] + KB2 * c[2044] + KB3 * c[3066];
    }
    bool cy = (y >= 1) & (y < 1023);
    if (cy & (x < 1020)) {
        const float* r = hx + (y - 1) * 1023 + x;
        v -= KF0 * r[0] + KF1 * r[1] + KF2 * r[2] + KF3 * r[3];
    }
    if (cy & (x >= 4)) {
        const float* r = hx + (y - 1) * 1023 + (x - 4);
        v -= KB0 * r[0] + KB1 * r[1] + KB2 * r[2] + KB3 * r[3];
    }
    return v;
}

// ---- scalar faraday reading E from LDS (verified v4) ----
#define EP 532
#define ES_AT(r, c) eS[((r) - y0 + 2) * EP + ((c) - xb + 4)]

__device__ __forceinline__ float far_hx_pt_lds(
    const float* eS, const float* __restrict__ hxp,
    int y0, int xb, int y, int x)
{
    float v = hxp[y * 1023 + x];
    if ((x >= 1) & (x < 1022)) {
        v -= 0.5f * ((ES_AT(y, x-1) - ES_AT(y, x) + ES_AT(y, x+1))
                     + (-ES_AT(y+1, x) + ES_AT(y+1, x+1))
                     + (ES_AT(y+2, x-1) - ES_AT(y+2, x) + ES_AT(y+2, x+1)));
    }
    if (x < 1021) {
        v -= KF0 * ES_AT(y+1, x) + KF1 * ES_AT(y+1, x+1)
           + KF2 * ES_AT(y+1, x+2) + KF3 * ES_AT(y+1, x+3);
    }
    if (x >= 2) {
        v -= KB0 * ES_AT(y+1, x-2) + KB1 * ES_AT(y+1, x-1)
           + KB2 * ES_AT(y+1, x) + KB3 * ES_AT(y+1, x+1);
    }
    return v;
}

__device__ __forceinline__ float far_hy_pt_lds(
    const float* eS, const float* __restrict__ hyp,
    int y0, int xb, int y, int x)
{
    float v = hyp[y * 1022 + x];
    if ((y >= 1) & (y < 1022)) {
        v += 0.5f * ((ES_AT(y-1, x) + ES_AT(y-1, x+2))
                     - (ES_AT(y, x) + ES_AT(y, x+1) + ES_AT(y, x+2))
                     + (ES_AT(y+1, x) + ES_AT(y+1, x+1) + ES_AT(y+1, x+2)));
    }
    if (y < 1021) {
        v += KF0 * ES_AT(y, x+1) + KF1 * ES_AT(y+1, x+1)
           + KF2 * ES_AT(y+2, x+1) + KF3 * ES_AT(y+3, x+1);
    }
    if (y >= 2) {
        v += KB0 * ES_AT(y-2, x+1) + KB1 * ES_AT(y-1, x+1)
           + KB2 * ES_AT(y, x+1) + KB3 * ES_AT(y+1, x+1);
    }
    return v;
}

// ---- fused amper+faraday for one 8x512 output strip ----
__global__ __launch_bounds__(256) void fused_k(
    const float* __restrict__ E, int sEb,
    const float* __restrict__ Hx, int sHxb,
    const float* __restrict__ Hy, int sHyb,
    float* __restrict__ Eo, int sEob,
    float* __restrict__ Hxo, int sHxob,
    float* __restrict__ Hyo, int sHyob)
{
    int xt = blockIdx.x;           // 0..1
    int b  = blockIdx.y;           // 0..7
    int s  = blockIdx.z;           // 0..127
    int y0 = s << 3;               // 8-row strip
    int xb = xt << 9;              // 512-col half

    const float* e  = E  + (size_t)b * sEb;
    const float* hx = Hx + (size_t)b * sHxb;
    const float* hy = Hy + (size_t)b * sHyb;
    float* eo  = Eo  + (size_t)b * sEob;
    float* hxo = Hxo + (size_t)b * sHxob;
    float* hyo = Hyo + (size_t)b * sHyob;

    __shared__ float eS[13 * EP];

    int tid = threadIdx.x;

    // ---- phase 1: E_new over rows y0-2..y0+10 (13), cols xb-4..xb+523 (132 f4)
    for (int idx = tid; idx < 13 * 132; idx += 256) {
        int i = idx / 132, j = idx - i * 132;
        int y  = y0 - 2 + i;
        int c0 = xb - 4 + (j << 2);
        if ((unsigned)y < 1024u) {
            f4 o;
            if ((y >= 4) & (y < 1020) & (c0 >= 4) & (c0 <= 1016)) {
                // verified v2 amper fast path
                float cA[6], cB[6], cC[6];
                const float* hyr = hy + (y - 2) * 1022 + (c0 - 2);
                LOAD6(cA, hyr);
                LOAD6(cB, hyr + 1022);
                LOAD6(cC, hyr + 2044);
                float km4[4], km3[4], kp1[4], kp2[4], kp3[4];
                const float* hyc = hy + (y - 4) * 1022 + (c0 - 1);
                LOAD4(km4, hyc);
                LOAD4(km3, hyc + 1022);
                LOAD4(kp1, hyc + 5 * 1022);
                LOAD4(kp2, hyc + 6 * 1022);
                LOAD4(kp3, hyc + 7 * 1022);
                float dA[6], dC[6], e12[12];
                const float* hxr = hx + (y - 2) * 1023 + (c0 - 2);
                LOAD6(dA, hxr);
                LOAD6(dC, hxr + 2046);
                const float* hxm = hx + (y - 1) * 1023 + (c0 - 4);
                LOAD4(&e12[0], hxm);
                LOAD4(&e12[4], hxm + 4);
                LOAD4(&e12[8], hxm + 8);
                f4 ev = ld4(e + y * 1024 + c0);
                #pragma unroll
                for (int k = 0; k < 4; ++k) {
                    float v = ev[k];
                    v += 0.5f * ((cA[k] + cA[k + 2])
                                 - (cB[k] + cB[k + 1] + cB[k + 2])
                                 + (cC[k] + cC[k + 1] + cC[k + 2]));
                    v -= 0.5f * ((dA[k] - dA[k + 1] + dA[k + 2])
                                 + (-e12[k + 3] + e12[k + 4])
                                 + (dC[k] - dC[k + 1] + dC[k + 2]));
                    v += KF0 * cC[k + 1] + KF1 * kp1[k] + KF2 * kp2[k] + KF3 * kp3[k];
                    v += KB0 * km4[k] + KB1 * km3[k] + KB2 * cA[k + 1] + KB3 * cB[k + 1];
                    v -= KF0 * e12[k + 4] + KF1 * e12[k + 5] + KF2 * e12[k + 6] + KF3 * e12[k + 7];
                    v -= KB0 * e12[k] + KB1 * e12[k + 1] + KB2 * e12[k + 2] + KB3 * e12[k + 3];
                    o[k] = v;
                }
            } else {
                #pragma unroll
                for (int k = 0; k < 4; ++k) {
                    int x = c0 + k;
                    o[k] = ((unsigned)x < 1024u) ? amper_pt(e, hx, hy, y, x) : 0.f;
                }
            }
            st4(&eS[i * EP + (c0 - xb + 4)], o);
            if ((y >= y0) & (y < y0 + 8) & (c0 >= xb) & (c0 <= xb + 508))
                st4(eo + y * 1024 + c0, o);
        }
    }
    __syncthreads();

    // ---- phase 2: faraday for rows y0..y0+7, cols xb..xb+511 (E from LDS)
    int tx = tid & 127, ty = tid >> 7;
    int c0 = xb + (tx << 2);
    bool cfast = (c0 >= 4) & (c0 <= 1016);

    #pragma unroll
    for (int rr = 0; rr < 4; ++rr) {
        int y = y0 + (ty << 2) + rr;

        // Hx part: y in [0,1022), x in [0,1023)
        if (y < 1022) {
            float* hxorow = hxo + y * 1023;
            if (cfast) {
                const float* er = &eS[(y - y0 + 2) * EP + (c0 - xb + 3)];
                float gA[6], gC[6], h9[9];
                LOAD6(gA, er);
                LOAD6(gC, er + 2 * EP);
                const float* em = &eS[(y - y0 + 3) * EP + (c0 - xb + 2)];
                LOAD4(&h9[0], em);
                LOAD4(&h9[4], em + 4);
                h9[8] = em[8];
                f4 hv = ld4(hx + y * 1023 + c0);
                f4 o;
                #pragma unroll
                for (int k = 0; k < 4; ++k) {
                    float v = hv[k];
                    v -= 0.5f * ((gA[k] - gA[k + 1] + gA[k + 2])
                                 + (-h9[k + 2] + h9[k + 3])
                                 + (gC[k] - gC[k + 1] + gC[k + 2]));
                    v -= KF0 * h9[k + 2] + KF1 * h9[k + 3] + KF2 * h9[k + 4] + KF3 * h9[k + 5];
                    v -= KB0 * h9[k] + KB1 * h9[k + 1] + KB2 * h9[k + 2] + KB3 * h9[k + 3];
                    o[k] = v;
                }
                st4(hxorow + c0, o);
            } else {
                #pragma unroll
                for (int k = 0; k < 4; ++k) {
                    int x = c0 + k;
                    if (x < 1023) hxorow[x] = far_hx_pt_lds(eS, hx, y0, xb, y, x);
                }
            }
        }

        // Hy part: y in [0,1023), x in [0,1022)
        if (y < 1023) {
            float* hyorow = hyo + y * 1022;
            if (cfast & (y >= 2) & (y <= 1020)) {
                const float* er = &eS[(y - y0 + 1) * EP + (c0 - xb + 4)];
                float mA[6], mB[6], mC[6], nA[4], nD[4], nE[4];
                LOAD6(mA, er);
                LOAD6(mB, er + EP);
                LOAD6(mC, er + 2 * EP);
                const float* en = &eS[(y - y0) * EP + (c0 - xb + 5)];
                LOAD4(nA, en);
                LOAD4(nD, en + 4 * EP);
                LOAD4(nE, en + 5 * EP);
                f4 hv = ld4(hy + y * 1022 + c0);
                f4 o;
                #pragma unroll
                for (int k = 0; k < 4; ++k) {
                    float v = hv[k];
                    v += 0.5f * ((mA[k] + mA[k + 2])
                                 - (mB[k] + mB[k + 1] + mB[k + 2])
                                 + (mC[k] + mC[k + 1] + mC[k + 2]));
                    v += KF0 * mB[k + 1] + KF1 * mC[k + 1] + KF2 * nD[k] + KF3 * nE[k];
                    v += KB0 * nA[k] + KB1 * mA[k + 1] + KB2 * mB[k + 1] + KB3 * mC[k + 1];
                    o[k] = v;
                }
                st4(hyorow + c0, o);
            } else {
                #pragma unroll
                for (int k = 0; k < 4; ++k) {
                    int x = c0 + k;
                    if (x < 1022) hyorow[x] = far_hy_pt_lds(eS, hy, y0, xb, y, x);
                }
            }
        }
    }
}

extern "C" void kernel_launch(void* const* d_in, const int* in_sizes, int n_in,
                              void* d_out, int out_size, void* d_ws, size_t ws_size,
                              hipStream_t stream)
{
    const float* E  = (const float*)d_in[0];
    const float* Hx = (const float*)d_in[1];
    const float* Hy = (const float*)d_in[2];

    float* out = (float*)d_out;
    float* Eo  = out;                      // 8 * 2048 * 1024
    float* Hxo = out + 16777216;           // 8 * 2044 * 1023
    float* Hyo = Hxo + 16728096;           // 8 * 2046 * 1022

    const int sE  = 1024 * 1024;
    const int sHx = 1022 * 1023;
    const int sHy = 1023 * 1022;
    const int sEo = 2 * 1024 * 1024;
    const int sHo = 2 * 1045506;

    dim3 blk(256, 1, 1);
    dim3 g(2, 8, 128);   // (x-half, batch, 8-row strip)

    // steps 1+2: E_n = amper(E,Hx,Hy); Hx_n,Hy_n = faraday(E_n,Hx,Hy)
    fused_k<<<g, blk, 0, stream>>>(E, sE, Hx, sHx, Hy, sHy,
                                   Eo, sEo, Hxo, sHo, Hyo, sHo);
    // steps 3+4: E_m = amper(E_n,Hx_n,Hy_n); Hx_m,Hy_m = faraday(E_m,...)
    fused_k<<<g, blk, 0, stream>>>(Eo, sEo, Hxo, sHo, Hyo, sHo,
                                   Eo + 1024 * 1024, sEo,
                                   Hxo + 1045506, sHo, Hyo + 1045506, sHo);
}